// Round 7
// baseline (4108.186 us; speedup 1.0000x reference)
//
#include <hip/hip_runtime.h>

// CausalTransformerBlock: B=4, S=4096, H=1024, NH=1, D_FF=4096, ktop=409.
// Dtypes: inputs f32, outputs f32 (r1/r2 evidence).
// r5 post-mortem: absmax 0.148 = top-k swaps from sigma_dlogit ~2e-4
// (wq/wk hi-only + bf16 vt). This round: full 2-split (bf16 hi+lo) on BOTH
// operands of every logit-critical GEMM (q,k,scores,PV,wo,router); vt f32.
// Predicted sigma ~1.2e-5 -> ~1.5% rows swapped -> absmax ~0.05.
// ws peak: 8*32MiB + 4MiB + 384KiB = 260.4MB (< 268.8MB proven in r1).

typedef unsigned short ushortT;
typedef short bf16x8 __attribute__((ext_vector_type(8)));
typedef float f32x4 __attribute__((ext_vector_type(4)));

#define SEQ 4096
#define HDIM 1024
#define TOK 16384
#define DFF 4096
#define KTOP 409

__device__ __forceinline__ float b2f(unsigned short u) {
    return __uint_as_float(((unsigned)u) << 16);
}
__device__ __forceinline__ unsigned short f2b(float f) {
    unsigned u = __float_as_uint(f);
    u += 0x7fffu + ((u >> 16) & 1u);   // RNE
    return (unsigned short)(u >> 16);
}

__device__ __forceinline__ float blkRedF(float v, float* red4) {
    #pragma unroll
    for (int o = 32; o; o >>= 1) v += __shfl_xor(v, o);
    if ((threadIdx.x & 63) == 0) red4[threadIdx.x >> 6] = v;
    __syncthreads();
    v = red4[0] + red4[1] + red4[2] + red4[3];
    __syncthreads();
    return v;
}
__device__ __forceinline__ int blkRedI(int v, int* red4) {
    #pragma unroll
    for (int o = 32; o; o >>= 1) v += __shfl_xor(v, o);
    if ((threadIdx.x & 63) == 0) red4[threadIdx.x >> 6] = v;
    __syncthreads();
    v = red4[0] + red4[1] + red4[2] + red4[3];
    __syncthreads();
    return v;
}

// -------- f32 -> bf16 hi (+ optional lo residual) convert -------------------
template<int HASLO>
__global__ __launch_bounds__(256) void cvt2_k(const float* __restrict__ s,
                                              ushortT* __restrict__ hi,
                                              ushortT* __restrict__ lo) {
    const int i = (blockIdx.x * 256 + threadIdx.x) * 4;
    float4 v = *(const float4*)(s + i);
    float vv[4] = {v.x, v.y, v.z, v.w};
    ushort4 h, l;
    unsigned short* hp = &h.x; unsigned short* lp = &l.x;
    #pragma unroll
    for (int j = 0; j < 4; ++j) {
        hp[j] = f2b(vv[j]);
        if constexpr (HASLO) lp[j] = f2b(vv[j] - b2f(hp[j]));
    }
    *(ushort4*)(hi + i) = h;
    if constexpr (HASLO) *(ushort4*)(lo + i) = l;
}

// ---------------- LayerNorm: f32 in -> f32 out ------------------------------
__global__ __launch_bounds__(256) void ln_k(const float* __restrict__ in,
                                            float* __restrict__ out,
                                            const float* __restrict__ g,
                                            const float* __restrict__ b) {
    __shared__ float red4[4];
    const long long row = blockIdx.x;
    const int t = threadIdx.x;
    float4 v = ((const float4*)(in + row * HDIM))[t];
    float x[4] = {v.x, v.y, v.z, v.w};
    float s = x[0] + x[1] + x[2] + x[3];
    s = blkRedF(s, red4);
    const float mean = s * (1.0f / HDIM);
    float vs = 0.f;
    #pragma unroll
    for (int k2 = 0; k2 < 4; ++k2) { float d = x[k2] - mean; vs += d * d; }
    vs = blkRedF(vs, red4);
    const float inv = 1.0f / sqrtf(vs * (1.0f / HDIM) + 1e-5f);
    float4 gv = ((const float4*)g)[t];
    float4 bv = ((const float4*)b)[t];
    float4 o;
    o.x = (x[0] - mean) * inv * gv.x + bv.x;
    o.y = (x[1] - mean) * inv * gv.y + bv.y;
    o.z = (x[2] - mean) * inv * gv.z + bv.z;
    o.w = (x[3] - mean) * inv * gv.w + bv.w;
    ((float4*)(out + row * HDIM))[t] = o;
}

// ------------- rank-3 causal-bias precompute (f32 h1) -----------------------
// bias[s,t] = e0[s]*u[t] + e1[s]*w[t] + z[t]
__global__ __launch_bounds__(256) void bias_pre(const float* __restrict__ h1,
        const float* __restrict__ cw, const float* __restrict__ cb,
        const float* __restrict__ ew, const float* __restrict__ eb,
        const float* __restrict__ st,
        float* __restrict__ e0, float* __restrict__ e1,
        float* __restrict__ uu, float* __restrict__ ww, float* __restrict__ zz) {
    const int tok = blockIdx.x * 4 + (threadIdx.x >> 6);
    const int L = threadIdx.x & 63;
    const float* h = h1 + (long long)tok * HDIM + L * 16;
    float d0 = 0, d1 = 0, du = 0, dw = 0, dz = 0;
    #pragma unroll
    for (int q = 0; q < 16; ++q) {
        float hv = h[q];
        d0 += hv * cw[L * 16 + q];
        d1 += hv * cw[HDIM + L * 16 + q];
        du += hv * ew[L * 16 + q];
        dw += hv * ew[HDIM + L * 16 + q];
        dz += hv * (eb[L * 16 + q] + eb[HDIM + L * 16 + q]);
    }
    #pragma unroll
    for (int o = 32; o; o >>= 1) {
        d0 += __shfl_xor(d0, o); d1 += __shfl_xor(d1, o);
        du += __shfl_xor(du, o); dw += __shfl_xor(dw, o); dz += __shfl_xor(dz, o);
    }
    if (L == 0) {
        e0[tok] = (d0 + cb[0]) * st[0];
        e1[tok] = (d1 + cb[1]) * st[1];
        uu[tok] = du; ww[tok] = dw; zz[tok] = dz;
    }
}

// ---------------- deterministic row-sum of f32 exp-scores -------------------
__global__ __launch_bounds__(256) void row_sum(const float* __restrict__ e,
                                               float* __restrict__ l) {
    __shared__ float red4[4];
    const long long row = blockIdx.x;
    const float4* p = (const float4*)(e + row * (long long)SEQ + threadIdx.x * 16);
    float s = 0.f;
    #pragma unroll
    for (int i = 0; i < 4; ++i) {
        float4 v = p[i];
        s += v.x + v.y + v.z + v.w;
    }
    s = blkRedF(s, red4);
    if (threadIdx.x == 0) l[row] = s;
}

// ---------------- normalize attn in place: e *= 1/l[row] (f32) --------------
__global__ __launch_bounds__(256) void attn_norm(float* __restrict__ attn,
                                                 const float* __restrict__ l) {
    const long long g = (long long)blockIdx.x * 256 + threadIdx.x;
    const long long base = g * 8;
    const float inv = 1.0f / l[base >> 12];
    float4 v0 = *(const float4*)(attn + base);
    float4 v1 = *(const float4*)(attn + base + 4);
    v0.x *= inv; v0.y *= inv; v0.z *= inv; v0.w *= inv;
    v1.x *= inv; v1.y *= inv; v1.z *= inv; v1.w *= inv;
    *(float4*)(attn + base) = v0;
    *(float4*)(attn + base + 4) = v1;
}

// ------- exact top-409 select + mask-apply (binary search on key bits) ------
__global__ __launch_bounds__(256) void topk_mask(const float* __restrict__ logits,
                                                 ushortT* __restrict__ ff) {
    __shared__ int red4[4];
    __shared__ int sc[256];
    const long long row = blockIdx.x;
    const int t = threadIdx.x;
    const float* lg = logits + row * (long long)DFF + t * 16;
    unsigned key[16];
    #pragma unroll
    for (int q4 = 0; q4 < 4; ++q4) {
        float4 v = ((const float4*)lg)[q4];
        float vv[4] = {v.x, v.y, v.z, v.w};
        #pragma unroll
        for (int j = 0; j < 4; ++j) {
            unsigned u = __float_as_uint(vv[j]);
            key[q4 * 4 + j] = (u & 0x80000000u) ? ~u : (u | 0x80000000u);
        }
    }
    unsigned T = 0;
    for (int bit = 31; bit >= 0; --bit) {
        unsigned cand = T | (1u << bit);
        int c = 0;
        #pragma unroll
        for (int q = 0; q < 16; ++q) c += (key[q] >= cand);
        c = blkRedI(c, red4);
        if (c >= KTOP) T = cand;
    }
    int cg = 0, eq = 0;
    #pragma unroll
    for (int q = 0; q < 16; ++q) { cg += (key[q] > T); eq += (key[q] == T); }
    cg = blkRedI(cg, red4);
    const int need = KTOP - cg;
    sc[t] = eq;
    __syncthreads();
    for (int o = 1; o < 256; o <<= 1) {
        int x = (t >= o) ? sc[t - o] : 0;
        __syncthreads();
        sc[t] += x;
        __syncthreads();
    }
    int pre = sc[t] - eq;   // exclusive prefix of equal-count, index order
    ushortT* fr = ff + row * (long long)DFF + t * 16;
    #pragma unroll
    for (int q = 0; q < 16; ++q) {
        bool sel = (key[q] > T) || ((key[q] == T) && (pre < need));
        if (key[q] == T) pre++;
        if (!sel) fr[q] = 0;
    }
}

// ---------------- unified NT GEMM: C[M,N] = A[M,K] * B[N,K]^T ----------------
// 128x128 tile, 4 waves, BK=32. Split-precision modes:
//  AMODE: 0=A bf16 gload_lds; 1=A f32 -> hi staged; 2=A f32 -> hi+lo staged;
//         3=A bf16 hi+lo arrays (gload_lds both)
//  BMODE: 0=B bf16 hi gload_lds; 1=B bf16 hi+lo arrays; 2=B f32 -> hi+lo staged
// Passes: hi*hi [+ hi*lo if BMODE!=0] [+ lo*hi if AMODE in {2,3}].
struct GemmP {
    const ushortT* A; const ushortT* A2; const float* Af;
    const ushortT* B; const ushortT* B2; const float* Bf;
    long long aBatch, bBatch, oBatch;
    int lda, ldb, K, ldo;
    void* out;
    const float* biasN; const float* biasM;
    const float *pe0, *pe1, *pu, *pw, *pz, *pl;
    const float* resF32;
    float scale;
};

// EPI: 2=f32 exp-scores(causal)  3=f32 PV*(1/l)  4=f32+biasN+resF32
//      5=gelu(.+biasN) bf16  6=f32+biasN  7=f32+biasN+resF32  8=f32+biasM
template<int EPI, int AMODE, int BMODE>
__global__ __launch_bounds__(256) void gemm_nt(GemmP p) {
    __shared__ ushortT Ahi[4096];
    __shared__ ushortT Bhi[4096];
    __shared__ ushortT Alo[(AMODE >= 2) ? 4096 : 8];
    __shared__ ushortT Blo[(BMODE != 0) ? 4096 : 8];
    const int tid = threadIdx.x;
    const int L = tid & 63;
    const int w = tid >> 6;
    const int wm = w >> 1, wn = w & 1;
    const int bn = blockIdx.x, bm = blockIdx.y, bz = blockIdx.z;

    f32x4 acc[4][4] = {};

    int kEnd = p.K;
    if constexpr (EPI == 2) { if (bn > bm) kEnd = 0; }
    if constexpr (EPI == 3) { kEnd = min(p.K, (bm + 1) * 128); }

    const int r0row = tid >> 2,         r0c = (tid & 3) * 8;
    const int r1row = (256 + tid) >> 2, r1c = (tid & 3) * 8;

    for (int k0 = 0; k0 < kEnd; k0 += 32) {
        // ---- stage A ----
        if constexpr (AMODE == 0 || AMODE == 3) {
            const ushortT* Ab = p.A + (long long)bz * p.aBatch + (long long)bm * 128 * p.lda;
            const ushortT* a0 = Ab + (long long)r0row * p.lda + k0 + r0c;
            const ushortT* a1 = Ab + (long long)r1row * p.lda + k0 + r1c;
            __builtin_amdgcn_global_load_lds(
                (const __attribute__((address_space(1))) void*)a0,
                (__attribute__((address_space(3))) void*)(Ahi + w * 512), 16, 0, 0);
            __builtin_amdgcn_global_load_lds(
                (const __attribute__((address_space(1))) void*)a1,
                (__attribute__((address_space(3))) void*)(Ahi + 2048 + w * 512), 16, 0, 0);
            if constexpr (AMODE == 3) {
                const ushortT* Ab2 = p.A2 + (long long)bz * p.aBatch + (long long)bm * 128 * p.lda;
                const ushortT* c0 = Ab2 + (long long)r0row * p.lda + k0 + r0c;
                const ushortT* c1 = Ab2 + (long long)r1row * p.lda + k0 + r1c;
                __builtin_amdgcn_global_load_lds(
                    (const __attribute__((address_space(1))) void*)c0,
                    (__attribute__((address_space(3))) void*)(Alo + w * 512), 16, 0, 0);
                __builtin_amdgcn_global_load_lds(
                    (const __attribute__((address_space(1))) void*)c1,
                    (__attribute__((address_space(3))) void*)(Alo + 2048 + w * 512), 16, 0, 0);
            }
        } else {
            const float* ap = p.Af + (long long)bz * p.aBatch
                            + ((long long)bm * 128 + (tid >> 1)) * p.lda
                            + k0 + (tid & 1) * 16;
            ushortT* dh = Ahi + (tid >> 1) * 32 + (tid & 1) * 16;
            ushortT* dl = Alo + (tid >> 1) * 32 + (tid & 1) * 16;
            #pragma unroll
            for (int q4 = 0; q4 < 4; ++q4) {
                float4 v = ((const float4*)ap)[q4];
                float vv[4] = {v.x, v.y, v.z, v.w};
                ushort4 h, l;
                unsigned short* hp = &h.x; unsigned short* lp = &l.x;
                #pragma unroll
                for (int j = 0; j < 4; ++j) {
                    hp[j] = f2b(vv[j]);
                    if constexpr (AMODE == 2) lp[j] = f2b(vv[j] - b2f(hp[j]));
                }
                *(ushort4*)(dh + q4 * 4) = h;
                if constexpr (AMODE == 2) *(ushort4*)(dl + q4 * 4) = l;
            }
        }
        // ---- stage B ----
        if constexpr (BMODE == 2) {
            const float* bp = p.Bf + (long long)bz * p.bBatch
                            + ((long long)bn * 128 + (tid >> 1)) * p.ldb
                            + k0 + (tid & 1) * 16;
            ushortT* dh = Bhi + (tid >> 1) * 32 + (tid & 1) * 16;
            ushortT* dl = Blo + (tid >> 1) * 32 + (tid & 1) * 16;
            #pragma unroll
            for (int q4 = 0; q4 < 4; ++q4) {
                float4 v = ((const float4*)bp)[q4];
                float vv[4] = {v.x, v.y, v.z, v.w};
                ushort4 h, l;
                unsigned short* hp = &h.x; unsigned short* lp = &l.x;
                #pragma unroll
                for (int j = 0; j < 4; ++j) {
                    hp[j] = f2b(vv[j]);
                    lp[j] = f2b(vv[j] - b2f(hp[j]));
                }
                *(ushort4*)(dh + q4 * 4) = h;
                *(ushort4*)(dl + q4 * 4) = l;
            }
        } else {
            const ushortT* Bb = p.B + (long long)bz * p.bBatch + (long long)bn * 128 * p.ldb;
            const ushortT* b0 = Bb + (long long)r0row * p.ldb + k0 + r0c;
            const ushortT* b1 = Bb + (long long)r1row * p.ldb + k0 + r1c;
            __builtin_amdgcn_global_load_lds(
                (const __attribute__((address_space(1))) void*)b0,
                (__attribute__((address_space(3))) void*)(Bhi + w * 512), 16, 0, 0);
            __builtin_amdgcn_global_load_lds(
                (const __attribute__((address_space(1))) void*)b1,
                (__attribute__((address_space(3))) void*)(Bhi + 2048 + w * 512), 16, 0, 0);
            if constexpr (BMODE == 1) {
                const ushortT* Bb2 = p.B2 + (long long)bz * p.bBatch + (long long)bn * 128 * p.ldb;
                const ushortT* c0 = Bb2 + (long long)r0row * p.ldb + k0 + r0c;
                const ushortT* c1 = Bb2 + (long long)r1row * p.ldb + k0 + r1c;
                __builtin_amdgcn_global_load_lds(
                    (const __attribute__((address_space(1))) void*)c0,
                    (__attribute__((address_space(3))) void*)(Blo + w * 512), 16, 0, 0);
                __builtin_amdgcn_global_load_lds(
                    (const __attribute__((address_space(1))) void*)c1,
                    (__attribute__((address_space(3))) void*)(Blo + 2048 + w * 512), 16, 0, 0);
            }
        }
        __syncthreads();
        {
            bf16x8 ah[4], bh[4];
            #pragma unroll
            for (int i = 0; i < 4; ++i)
                ah[i] = *(const bf16x8*)(Ahi + (wm * 64 + i * 16 + (L & 15)) * 32 + (L >> 4) * 8);
            #pragma unroll
            for (int j = 0; j < 4; ++j)
                bh[j] = *(const bf16x8*)(Bhi + (wn * 64 + j * 16 + (L & 15)) * 32 + (L >> 4) * 8);
            #pragma unroll
            for (int i = 0; i < 4; ++i)
                #pragma unroll
                for (int j = 0; j < 4; ++j)
                    acc[i][j] = __builtin_amdgcn_mfma_f32_16x16x32_bf16(ah[i], bh[j], acc[i][j], 0, 0, 0);
            if constexpr (BMODE != 0) {
                bf16x8 bl[4];
                #pragma unroll
                for (int j = 0; j < 4; ++j)
                    bl[j] = *(const bf16x8*)(Blo + (wn * 64 + j * 16 + (L & 15)) * 32 + (L >> 4) * 8);
                #pragma unroll
                for (int i = 0; i < 4; ++i)
                    #pragma unroll
                    for (int j = 0; j < 4; ++j)
                        acc[i][j] = __builtin_amdgcn_mfma_f32_16x16x32_bf16(ah[i], bl[j], acc[i][j], 0, 0, 0);
            }
            if constexpr (AMODE >= 2) {
                bf16x8 al[4];
                #pragma unroll
                for (int i = 0; i < 4; ++i)
                    al[i] = *(const bf16x8*)(Alo + (wm * 64 + i * 16 + (L & 15)) * 32 + (L >> 4) * 8);
                #pragma unroll
                for (int i = 0; i < 4; ++i)
                    #pragma unroll
                    for (int j = 0; j < 4; ++j)
                        acc[i][j] = __builtin_amdgcn_mfma_f32_16x16x32_bf16(al[i], bh[j], acc[i][j], 0, 0, 0);
            }
        }
        __syncthreads();
    }

    const long long obase = (long long)bz * p.oBatch;
    ushortT* Ob = (ushortT*)p.out;
    float* Of = (float*)p.out;

    #pragma unroll
    for (int i = 0; i < 4; ++i) {
        #pragma unroll
        for (int r = 0; r < 4; ++r) {
            const int gm = bm * 128 + wm * 64 + i * 16 + ((L >> 4) << 2) + r;
            float rowA = 0.f, rowB = 0.f, inv = 1.f;
            if constexpr (EPI == 8) rowA = p.biasM[gm];
            if constexpr (EPI == 2) { rowA = p.pe0[bz * SEQ + gm]; rowB = p.pe1[bz * SEQ + gm]; }
            if constexpr (EPI == 3) inv = 1.0f / p.pl[bz * SEQ + gm];
            #pragma unroll
            for (int j = 0; j < 4; ++j) {
                const int gn = bn * 128 + wn * 64 + j * 16 + (L & 15);
                float v = acc[i][j][r];
                const long long oidx = obase + (long long)gm * p.ldo + gn;
                if constexpr (EPI == 2) {
                    float s = v * p.scale + rowA * p.pu[bz * SEQ + gn]
                            + rowB * p.pw[bz * SEQ + gn] + p.pz[bz * SEQ + gn];
                    Of[oidx] = (gn <= gm) ? __expf(s) : 0.f;
                } else if constexpr (EPI == 3) {
                    Of[oidx] = v * inv;
                } else if constexpr (EPI == 4) {
                    Of[oidx] = v + p.biasN[gn] + p.resF32[(long long)gm * p.ldo + gn];
                } else if constexpr (EPI == 5) {
                    float tt = v + p.biasN[gn];
                    Ob[oidx] = f2b(0.5f * tt * (1.0f + erff(tt * 0.70710678118654752f)));
                } else if constexpr (EPI == 6) {
                    Of[oidx] = v + p.biasN[gn];
                } else if constexpr (EPI == 7) {
                    Of[oidx] = v + p.biasN[gn] + p.resF32[(long long)gm * p.ldo + gn];
                } else if constexpr (EPI == 8) {
                    Of[oidx] = v + rowA;
                }
            }
        }
    }
}

// ------------------------------- host driver --------------------------------
extern "C" void kernel_launch(void* const* d_in, const int* in_sizes, int n_in,
                              void* d_out, int out_size, void* d_ws, size_t ws_size,
                              hipStream_t stream) {
    (void)in_sizes; (void)n_in; (void)out_size; (void)ws_size;
    const float* x    = (const float*)d_in[0];
    const float* wq   = (const float*)d_in[2];
    const float* bq   = (const float*)d_in[3];
    const float* wk   = (const float*)d_in[4];
    const float* bk   = (const float*)d_in[5];
    const float* wv   = (const float*)d_in[6];
    const float* bv   = (const float*)d_in[7];
    const float* wo   = (const float*)d_in[8];
    const float* bo   = (const float*)d_in[9];
    const float* ln1g = (const float*)d_in[10];
    const float* ln1b = (const float*)d_in[11];
    const float* ln2g = (const float*)d_in[12];
    const float* ln2b = (const float*)d_in[13];
    const float* fc1w = (const float*)d_in[14];
    const float* fc1b = (const float*)d_in[15];
    const float* fc2w = (const float*)d_in[16];
    const float* fc2b = (const float*)d_in[17];
    const float* rww  = (const float*)d_in[18];
    const float* rwb  = (const float*)d_in[19];
    const float* cw   = (const float*)d_in[20];
    const float* cb   = (const float*)d_in[21];
    const float* ew   = (const float*)d_in[22];
    const float* eb   = (const float*)d_in[23];
    const float* st   = (const float*)d_in[24];

    char* ws = (char*)d_ws;
    const size_t MB32 = 33554432;
    // slots (32MB): 0-1 qf -> x1 | 2-3 kf -> h2 | 4-5 h1f -> ctx -> {logc,ffc}
    // 6-7 vtf -> fw(FFN weights) | tail: wjit(4MB) + smalls.
    float* qf  = (float*)(ws + 0 * MB32);
    float* kf  = (float*)(ws + 2 * MB32);
    float* h1f = (float*)(ws + 4 * MB32);
    float* vtf = (float*)(ws + 6 * MB32);
    float* ctx = (float*)(ws + 4 * MB32);
    float* x1  = (float*)(ws + 0 * MB32);
    float* h2  = (float*)(ws + 2 * MB32);
    float*   logc = (float*)(ws + 4 * MB32);
    ushortT* ffc  = (ushortT*)(ws + 5 * MB32);
    ushortT* fw   = (ushortT*)(ws + 6 * MB32);
    char* tail = ws + 8 * MB32;
    ushortT* whi = (ushortT*)(tail);                    // 2MB JIT weight hi
    ushortT* wlo = (ushortT*)(tail + 2097152);          // 2MB JIT weight lo
    char* sm = tail + 4194304;
    float* e0v = (float*)(sm);
    float* e1v = (float*)(sm + 1 * 65536);
    float* uu  = (float*)(sm + 2 * 65536);
    float* wwp = (float*)(sm + 3 * 65536);
    float* zz  = (float*)(sm + 4 * 65536);
    float* lrow = (float*)(sm + 5 * 65536);

    const int NW = HDIM * HDIM;
    const int NF = DFF * HDIM;
    ushortT* fc1h = fw;
    ushortT* fc2h = fw + 1 * (size_t)NF;
    ushortT* rwh  = fw + 2 * (size_t)NF;
    ushortT* rwl  = fw + 3 * (size_t)NF;

    float* outx = (float*)d_out;
    float* attn = outx + (size_t)TOK * HDIM;    // f32 [B,1,S,S]

    // --- attention sub-block ---
    ln_k<<<TOK, 256, 0, stream>>>(x, h1f, ln1g, ln1b);

    // q = h1*wq^T + bq  (h1 2-split x wq hi+lo JIT)
    cvt2_k<1><<<NW / 1024, 256, 0, stream>>>(wq, whi, wlo);
    GemmP pq{};
    pq.Af = h1f; pq.B = whi; pq.B2 = wlo;
    pq.lda = HDIM; pq.ldb = HDIM; pq.K = HDIM; pq.ldo = HDIM;
    pq.out = qf; pq.biasN = bq;
    gemm_nt<6, 2, 1><<<dim3(8, 128, 1), 256, 0, stream>>>(pq);

    cvt2_k<1><<<NW / 1024, 256, 0, stream>>>(wk, whi, wlo);
    pq.out = kf; pq.biasN = bk;
    gemm_nt<6, 2, 1><<<dim3(8, 128, 1), 256, 0, stream>>>(pq);

    // vt[d,t] = wv[d,:]*h1[t,:] + bv[d]  (f32 out; wv hi+lo x h1 2-split)
    cvt2_k<1><<<NW / 1024, 256, 0, stream>>>(wv, whi, wlo);
    GemmP pv{};
    pv.A = whi; pv.A2 = wlo; pv.Bf = h1f;
    pv.lda = HDIM; pv.ldb = HDIM; pv.K = HDIM; pv.ldo = SEQ;
    pv.aBatch = 0; pv.bBatch = (long long)SEQ * HDIM; pv.oBatch = (long long)HDIM * SEQ;
    pv.out = vtf; pv.biasM = bv;
    gemm_nt<8, 3, 2><<<dim3(32, 8, 4), 256, 0, stream>>>(pv);

    bias_pre<<<4096, 256, 0, stream>>>(h1f, cw, cb, ew, eb, st, e0v, e1v, uu, wwp, zz);

    // scores -> exp (q 2-split x k 2-split)
    GemmP ps{};
    ps.Af = qf; ps.Bf = kf; ps.lda = HDIM; ps.ldb = HDIM; ps.K = HDIM; ps.ldo = SEQ;
    ps.aBatch = (long long)SEQ * HDIM; ps.bBatch = (long long)SEQ * HDIM;
    ps.oBatch = (long long)SEQ * SEQ;
    ps.out = attn; ps.scale = 0.03125f;  // 1/sqrt(1024)
    ps.pe0 = e0v; ps.pe1 = e1v; ps.pu = uu; ps.pw = wwp; ps.pz = zz;
    gemm_nt<2, 2, 2><<<dim3(32, 32, 4), 256, 0, stream>>>(ps);

    row_sum<<<TOK, 256, 0, stream>>>(attn, lrow);

    // ctx = (e * vt^T) / l  (e 2-split x vt 2-split)
    GemmP pp{};
    pp.Af = attn; pp.Bf = vtf; pp.lda = SEQ; pp.ldb = SEQ; pp.K = SEQ; pp.ldo = HDIM;
    pp.aBatch = (long long)SEQ * SEQ; pp.bBatch = (long long)HDIM * SEQ;
    pp.oBatch = (long long)SEQ * HDIM;
    pp.out = ctx; pp.pl = lrow;
    gemm_nt<3, 2, 2><<<dim3(8, 32, 4), 256, 0, stream>>>(pp);

    attn_norm<<<32768, 256, 0, stream>>>(attn, lrow);

    // x1 = x + ctx*wo^T + bo  (ctx 2-split x wo hi+lo JIT)
    cvt2_k<1><<<NW / 1024, 256, 0, stream>>>(wo, whi, wlo);
    GemmP po{};
    po.Af = ctx; po.B = whi; po.B2 = wlo;
    po.lda = HDIM; po.ldb = HDIM; po.K = HDIM; po.ldo = HDIM;
    po.out = x1; po.biasN = bo; po.resF32 = x;
    gemm_nt<4, 2, 1><<<dim3(8, 128, 1), 256, 0, stream>>>(po);

    // --- sparse FFN sub-block ---
    ln_k<<<TOK, 256, 0, stream>>>(x1, h2, ln2g, ln2b);

    cvt2_k<0><<<NF / 1024, 256, 0, stream>>>(fc1w, fc1h, nullptr);
    cvt2_k<0><<<NF / 1024, 256, 0, stream>>>(fc2w, fc2h, nullptr);
    cvt2_k<1><<<NF / 1024, 256, 0, stream>>>(rww, rwh, rwl);

    for (int c = 0; c < 8; ++c) {
        float* h2c = h2 + (size_t)c * 2048 * HDIM;
        GemmP pf{};
        pf.Af = h2c; pf.B = fc1h; pf.lda = HDIM; pf.ldb = HDIM; pf.K = HDIM; pf.ldo = DFF;
        pf.out = ffc; pf.biasN = fc1b;
        gemm_nt<5, 1, 0><<<dim3(32, 16, 1), 256, 0, stream>>>(pf);

        GemmP pr{};
        pr.Af = h2c; pr.B = rwh; pr.B2 = rwl;
        pr.lda = HDIM; pr.ldb = HDIM; pr.K = HDIM; pr.ldo = DFF;
        pr.out = logc; pr.biasN = rwb;
        gemm_nt<6, 2, 1><<<dim3(32, 16, 1), 256, 0, stream>>>(pr);

        topk_mask<<<2048, 256, 0, stream>>>(logc, ffc);

        GemmP p2{};
        p2.A = ffc; p2.B = fc2h; p2.lda = DFF; p2.ldb = DFF; p2.K = DFF; p2.ldo = HDIM;
        p2.out = outx + (size_t)c * 2048 * HDIM; p2.biasN = fc2b;
        p2.resF32 = x1 + (size_t)c * 2048 * HDIM;
        gemm_nt<7, 0, 0><<<dim3(8, 16, 1), 256, 0, stream>>>(p2);
    }
}

// Round 8
// 3520.358 us; speedup vs baseline: 1.1670x; 1.1670x over previous
//
#include <hip/hip_runtime.h>

// CausalTransformerBlock: B=4, S=4096, H=1024, NH=1, D_FF=4096, ktop=409.
// r7 PASSED (4108us, absmax 0.097). r8: kill VALU staging (pre-split all
// GEMM-feeding intermediates to bf16 hi+lo at the producer; all GEMM staging
// via global_load_lds) + XOR chunk-swizzle (source+read, LDS dest linear)
// to fix the 4-way ds_read_b128 bank conflict (3.46e7/dispatch).
// Numerics identical to r7 except bias_pre reads h1 as hi+lo (<=2^-17 rel).
// ws: 8*32MiB + 4MiB + 384KiB = 273,022,976 B (proven in r7).

typedef unsigned short ushortT;
typedef short bf16x8 __attribute__((ext_vector_type(8)));
typedef float f32x4 __attribute__((ext_vector_type(4)));
typedef unsigned short us8 __attribute__((ext_vector_type(8)));

#define SEQ 4096
#define HDIM 1024
#define TOK 16384
#define DFF 4096
#define KTOP 409

__device__ __forceinline__ float b2f(unsigned short u) {
    return __uint_as_float(((unsigned)u) << 16);
}
__device__ __forceinline__ unsigned short f2b(float f) {
    unsigned u = __float_as_uint(f);
    u += 0x7fffu + ((u >> 16) & 1u);   // RNE
    return (unsigned short)(u >> 16);
}

__device__ __forceinline__ float blkRedF(float v, float* red4) {
    #pragma unroll
    for (int o = 32; o; o >>= 1) v += __shfl_xor(v, o);
    if ((threadIdx.x & 63) == 0) red4[threadIdx.x >> 6] = v;
    __syncthreads();
    v = red4[0] + red4[1] + red4[2] + red4[3];
    __syncthreads();
    return v;
}
__device__ __forceinline__ int blkRedI(int v, int* red4) {
    #pragma unroll
    for (int o = 32; o; o >>= 1) v += __shfl_xor(v, o);
    if ((threadIdx.x & 63) == 0) red4[threadIdx.x >> 6] = v;
    __syncthreads();
    v = red4[0] + red4[1] + red4[2] + red4[3];
    __syncthreads();
    return v;
}

// -------- f32 -> bf16 hi (+ optional lo residual) convert -------------------
template<int HASLO>
__global__ __launch_bounds__(256) void cvt2_k(const float* __restrict__ s,
                                              ushortT* __restrict__ hi,
                                              ushortT* __restrict__ lo) {
    const int i = (blockIdx.x * 256 + threadIdx.x) * 4;
    float4 v = *(const float4*)(s + i);
    float vv[4] = {v.x, v.y, v.z, v.w};
    ushort4 h, l;
    unsigned short* hp = &h.x; unsigned short* lp = &l.x;
    #pragma unroll
    for (int j = 0; j < 4; ++j) {
        hp[j] = f2b(vv[j]);
        if constexpr (HASLO) lp[j] = f2b(vv[j] - b2f(hp[j]));
    }
    *(ushort4*)(hi + i) = h;
    if constexpr (HASLO) *(ushort4*)(lo + i) = l;
}

// ---------------- LayerNorm: f32 in -> bf16 hi+lo out ------------------------
__global__ __launch_bounds__(256) void ln_k(const float* __restrict__ in,
                                            ushortT* __restrict__ ohi,
                                            ushortT* __restrict__ olo,
                                            const float* __restrict__ g,
                                            const float* __restrict__ b) {
    __shared__ float red4[4];
    const long long row = blockIdx.x;
    const int t = threadIdx.x;
    float4 v = ((const float4*)(in + row * HDIM))[t];
    float x[4] = {v.x, v.y, v.z, v.w};
    float s = x[0] + x[1] + x[2] + x[3];
    s = blkRedF(s, red4);
    const float mean = s * (1.0f / HDIM);
    float vs = 0.f;
    #pragma unroll
    for (int k2 = 0; k2 < 4; ++k2) { float d = x[k2] - mean; vs += d * d; }
    vs = blkRedF(vs, red4);
    const float inv = 1.0f / sqrtf(vs * (1.0f / HDIM) + 1e-5f);
    float4 gv = ((const float4*)g)[t];
    float4 bv = ((const float4*)b)[t];
    float o[4];
    o[0] = (x[0] - mean) * inv * gv.x + bv.x;
    o[1] = (x[1] - mean) * inv * gv.y + bv.y;
    o[2] = (x[2] - mean) * inv * gv.z + bv.z;
    o[3] = (x[3] - mean) * inv * gv.w + bv.w;
    ushort4 h, l;
    unsigned short* hp = &h.x; unsigned short* lp = &l.x;
    #pragma unroll
    for (int j = 0; j < 4; ++j) {
        hp[j] = f2b(o[j]);
        lp[j] = f2b(o[j] - b2f(hp[j]));
    }
    ((ushort4*)(ohi + row * HDIM))[t] = h;
    ((ushort4*)(olo + row * HDIM))[t] = l;
}

// ------------- rank-3 causal-bias precompute (h1 = hi+lo bf16) --------------
// bias[s,t] = e0[s]*u[t] + e1[s]*w[t] + z[t]
__global__ __launch_bounds__(256) void bias_pre(const ushortT* __restrict__ hhi,
        const ushortT* __restrict__ hlo,
        const float* __restrict__ cw, const float* __restrict__ cb,
        const float* __restrict__ ew, const float* __restrict__ eb,
        const float* __restrict__ st,
        float* __restrict__ e0, float* __restrict__ e1,
        float* __restrict__ uu, float* __restrict__ ww, float* __restrict__ zz) {
    const int tok = blockIdx.x * 4 + (threadIdx.x >> 6);
    const int L = threadIdx.x & 63;
    const long long base = (long long)tok * HDIM + L * 16;
    float d0 = 0, d1 = 0, du = 0, dw = 0, dz = 0;
    #pragma unroll
    for (int q = 0; q < 16; ++q) {
        float hv = b2f(hhi[base + q]) + b2f(hlo[base + q]);
        d0 += hv * cw[L * 16 + q];
        d1 += hv * cw[HDIM + L * 16 + q];
        du += hv * ew[L * 16 + q];
        dw += hv * ew[HDIM + L * 16 + q];
        dz += hv * (eb[L * 16 + q] + eb[HDIM + L * 16 + q]);
    }
    #pragma unroll
    for (int o = 32; o; o >>= 1) {
        d0 += __shfl_xor(d0, o); d1 += __shfl_xor(d1, o);
        du += __shfl_xor(du, o); dw += __shfl_xor(dw, o); dz += __shfl_xor(dz, o);
    }
    if (L == 0) {
        e0[tok] = (d0 + cb[0]) * st[0];
        e1[tok] = (d1 + cb[1]) * st[1];
        uu[tok] = du; ww[tok] = dw; zz[tok] = dz;
    }
}

// ---------------- deterministic row-sum of f32 exp-scores -------------------
__global__ __launch_bounds__(256) void row_sum(const float* __restrict__ e,
                                               float* __restrict__ l) {
    __shared__ float red4[4];
    const long long row = blockIdx.x;
    const float4* p = (const float4*)(e + row * (long long)SEQ + threadIdx.x * 16);
    float s = 0.f;
    #pragma unroll
    for (int i = 0; i < 4; ++i) {
        float4 v = p[i];
        s += v.x + v.y + v.z + v.w;
    }
    s = blkRedF(s, red4);
    if (threadIdx.x == 0) l[row] = s;
}

// ---------------- normalize attn in place: e *= 1/l[row] (f32) --------------
__global__ __launch_bounds__(256) void attn_norm(float* __restrict__ attn,
                                                 const float* __restrict__ l) {
    const long long g = (long long)blockIdx.x * 256 + threadIdx.x;
    const long long base = g * 8;
    const float inv = 1.0f / l[base >> 12];
    float4 v0 = *(const float4*)(attn + base);
    float4 v1 = *(const float4*)(attn + base + 4);
    v0.x *= inv; v0.y *= inv; v0.z *= inv; v0.w *= inv;
    v1.x *= inv; v1.y *= inv; v1.z *= inv; v1.w *= inv;
    *(float4*)(attn + base) = v0;
    *(float4*)(attn + base + 4) = v1;
}

// ------- exact top-409 select + mask-apply (binary search on key bits) ------
__global__ __launch_bounds__(256) void topk_mask(const float* __restrict__ logits,
                                                 ushortT* __restrict__ ff) {
    __shared__ int red4[4];
    __shared__ int sc[256];
    const long long row = blockIdx.x;
    const int t = threadIdx.x;
    const float* lg = logits + row * (long long)DFF + t * 16;
    unsigned key[16];
    #pragma unroll
    for (int q4 = 0; q4 < 4; ++q4) {
        float4 v = ((const float4*)lg)[q4];
        float vv[4] = {v.x, v.y, v.z, v.w};
        #pragma unroll
        for (int j = 0; j < 4; ++j) {
            unsigned u = __float_as_uint(vv[j]);
            key[q4 * 4 + j] = (u & 0x80000000u) ? ~u : (u | 0x80000000u);
        }
    }
    unsigned T = 0;
    for (int bit = 31; bit >= 0; --bit) {
        unsigned cand = T | (1u << bit);
        int c = 0;
        #pragma unroll
        for (int q = 0; q < 16; ++q) c += (key[q] >= cand);
        c = blkRedI(c, red4);
        if (c >= KTOP) T = cand;
    }
    int cg = 0, eq = 0;
    #pragma unroll
    for (int q = 0; q < 16; ++q) { cg += (key[q] > T); eq += (key[q] == T); }
    cg = blkRedI(cg, red4);
    const int need = KTOP - cg;
    sc[t] = eq;
    __syncthreads();
    for (int o = 1; o < 256; o <<= 1) {
        int x = (t >= o) ? sc[t - o] : 0;
        __syncthreads();
        sc[t] += x;
        __syncthreads();
    }
    int pre = sc[t] - eq;   // exclusive prefix of equal-count, index order
    ushortT* fr = ff + row * (long long)DFF + t * 16;
    #pragma unroll
    for (int q = 0; q < 16; ++q) {
        bool sel = (key[q] > T) || ((key[q] == T) && (pre < need));
        if (key[q] == T) pre++;
        if (!sel) fr[q] = 0;
    }
}

// ---------------- unified NT GEMM: C[M,N] = A[M,K] * B[N,K]^T ----------------
// 128x128 tile, 4 waves, BK=32, global_load_lds(16B), XOR chunk-swizzle.
//  AMODE: 0=A bf16 hi gload_lds; 2=A f32 -> hi+lo VALU-staged; 3=A hi+lo gload_lds
//  BMODE: 0=B bf16 hi gload_lds; 1=B hi+lo gload_lds
// Passes: hi*hi [+ hi*lo if BMODE==1] [+ lo*hi if AMODE>=2].
struct GemmP {
    const ushortT* A; const ushortT* A2; const float* Af;
    const ushortT* B; const ushortT* B2;
    long long aBatch, bBatch, oBatch;
    int lda, ldb, K, ldo;
    void* out; void* out2;
    const float* biasN; const float* biasM;
    const float *pe0, *pe1, *pu, *pw, *pz, *pl;
    const float* resF32;
    float scale;
};

// EPI: 2=f32 exp-scores(causal)  3=hi+lo PV*(1/l)  4=f32+biasN+resF32
//      5=gelu(.+biasN) bf16  6=hi+lo +biasN  8=hi+lo +biasM  9=f32+biasN
template<int EPI, int AMODE, int BMODE>
__global__ __launch_bounds__(256) void gemm_nt(GemmP p) {
    __shared__ ushortT Ahi[4096];
    __shared__ ushortT Bhi[4096];
    __shared__ ushortT Alo[(AMODE >= 2) ? 4096 : 8];
    __shared__ ushortT Blo[(BMODE == 1) ? 4096 : 8];
    const int tid = threadIdx.x;
    const int L = tid & 63;
    const int w = tid >> 6;
    const int wm = w >> 1, wn = w & 1;
    const int bn = blockIdx.x, bm = blockIdx.y, bz = blockIdx.z;

    f32x4 acc[4][4] = {};

    int kEnd = p.K;
    if constexpr (EPI == 2) { if (bn > bm) kEnd = 0; }
    if constexpr (EPI == 3) { kEnd = min(p.K, (bm + 1) * 128); }

    // gload_lds dest is linear (lane*16B); pre-swizzle the SOURCE chunk so
    // LDS[row][chunk] = global[row][chunk ^ (row&3)]; reads apply same XOR.
    const int r0row = tid >> 2;
    const int r1row = 64 + r0row;
    const int rc   = ((tid & 3) ^ ((tid >> 2) & 3)) * 8;  // source chunk (elems)
    const int qsw  = ((L >> 4) ^ (L & 3)) * 8;            // read chunk (elems)

    for (int k0 = 0; k0 < kEnd; k0 += 32) {
        // ---- stage A ----
        if constexpr (AMODE != 2) {
            const ushortT* Ab = p.A + (long long)bz * p.aBatch
                              + (long long)bm * 128 * p.lda + k0 + rc;
            __builtin_amdgcn_global_load_lds(
                (const __attribute__((address_space(1))) void*)(Ab + (long long)r0row * p.lda),
                (__attribute__((address_space(3))) void*)(Ahi + w * 512), 16, 0, 0);
            __builtin_amdgcn_global_load_lds(
                (const __attribute__((address_space(1))) void*)(Ab + (long long)r1row * p.lda),
                (__attribute__((address_space(3))) void*)(Ahi + 2048 + w * 512), 16, 0, 0);
            if constexpr (AMODE == 3) {
                const ushortT* Ab2 = p.A2 + (long long)bz * p.aBatch
                                   + (long long)bm * 128 * p.lda + k0 + rc;
                __builtin_amdgcn_global_load_lds(
                    (const __attribute__((address_space(1))) void*)(Ab2 + (long long)r0row * p.lda),
                    (__attribute__((address_space(3))) void*)(Alo + w * 512), 16, 0, 0);
                __builtin_amdgcn_global_load_lds(
                    (const __attribute__((address_space(1))) void*)(Ab2 + (long long)r1row * p.lda),
                    (__attribute__((address_space(3))) void*)(Alo + 2048 + w * 512), 16, 0, 0);
            }
        } else {
            const int arow = tid >> 1;
            const float* ap = p.Af + (long long)bz * p.aBatch
                            + ((long long)bm * 128 + arow) * p.lda
                            + k0 + (tid & 1) * 16;
            #pragma unroll
            for (int cc = 0; cc < 2; ++cc) {
                const int c = (tid & 1) * 2 + cc;
                const int cs = (c ^ (arow & 3)) * 8;        // swizzled dest chunk
                float4 v0 = ((const float4*)ap)[cc * 2];
                float4 v1 = ((const float4*)ap)[cc * 2 + 1];
                float vv[8] = {v0.x, v0.y, v0.z, v0.w, v1.x, v1.y, v1.z, v1.w};
                us8 h, l;
                #pragma unroll
                for (int j = 0; j < 8; ++j) {
                    h[j] = f2b(vv[j]);
                    l[j] = f2b(vv[j] - b2f(h[j]));
                }
                *(us8*)(Ahi + arow * 32 + cs) = h;
                *(us8*)(Alo + arow * 32 + cs) = l;
            }
        }
        // ---- stage B ----
        {
            const ushortT* Bb = p.B + (long long)bz * p.bBatch
                              + (long long)bn * 128 * p.ldb + k0 + rc;
            __builtin_amdgcn_global_load_lds(
                (const __attribute__((address_space(1))) void*)(Bb + (long long)r0row * p.ldb),
                (__attribute__((address_space(3))) void*)(Bhi + w * 512), 16, 0, 0);
            __builtin_amdgcn_global_load_lds(
                (const __attribute__((address_space(1))) void*)(Bb + (long long)r1row * p.ldb),
                (__attribute__((address_space(3))) void*)(Bhi + 2048 + w * 512), 16, 0, 0);
            if constexpr (BMODE == 1) {
                const ushortT* Bb2 = p.B2 + (long long)bz * p.bBatch
                                   + (long long)bn * 128 * p.ldb + k0 + rc;
                __builtin_amdgcn_global_load_lds(
                    (const __attribute__((address_space(1))) void*)(Bb2 + (long long)r0row * p.ldb),
                    (__attribute__((address_space(3))) void*)(Blo + w * 512), 16, 0, 0);
                __builtin_amdgcn_global_load_lds(
                    (const __attribute__((address_space(1))) void*)(Bb2 + (long long)r1row * p.ldb),
                    (__attribute__((address_space(3))) void*)(Blo + 2048 + w * 512), 16, 0, 0);
            }
        }
        __syncthreads();
        {
            bf16x8 ah[4], bh[4];
            #pragma unroll
            for (int i = 0; i < 4; ++i)
                ah[i] = *(const bf16x8*)(Ahi + (wm * 64 + i * 16 + (L & 15)) * 32 + qsw);
            #pragma unroll
            for (int j = 0; j < 4; ++j)
                bh[j] = *(const bf16x8*)(Bhi + (wn * 64 + j * 16 + (L & 15)) * 32 + qsw);
            #pragma unroll
            for (int i = 0; i < 4; ++i)
                #pragma unroll
                for (int j = 0; j < 4; ++j)
                    acc[i][j] = __builtin_amdgcn_mfma_f32_16x16x32_bf16(ah[i], bh[j], acc[i][j], 0, 0, 0);
            if constexpr (BMODE == 1) {
                bf16x8 bl[4];
                #pragma unroll
                for (int j = 0; j < 4; ++j)
                    bl[j] = *(const bf16x8*)(Blo + (wn * 64 + j * 16 + (L & 15)) * 32 + qsw);
                #pragma unroll
                for (int i = 0; i < 4; ++i)
                    #pragma unroll
                    for (int j = 0; j < 4; ++j)
                        acc[i][j] = __builtin_amdgcn_mfma_f32_16x16x32_bf16(ah[i], bl[j], acc[i][j], 0, 0, 0);
            }
            if constexpr (AMODE >= 2) {
                bf16x8 al[4];
                #pragma unroll
                for (int i = 0; i < 4; ++i)
                    al[i] = *(const bf16x8*)(Alo + (wm * 64 + i * 16 + (L & 15)) * 32 + qsw);
                #pragma unroll
                for (int i = 0; i < 4; ++i)
                    #pragma unroll
                    for (int j = 0; j < 4; ++j)
                        acc[i][j] = __builtin_amdgcn_mfma_f32_16x16x32_bf16(al[i], bh[j], acc[i][j], 0, 0, 0);
            }
        }
        __syncthreads();
    }

    const long long obase = (long long)bz * p.oBatch;
    float* Of = (float*)p.out;
    ushortT* Oh = (ushortT*)p.out;
    ushortT* Ol = (ushortT*)p.out2;

    int gnv[4];
    #pragma unroll
    for (int j = 0; j < 4; ++j) gnv[j] = bn * 128 + wn * 64 + j * 16 + (L & 15);
    float c0[4], c1[4], c2[4];
    #pragma unroll
    for (int j = 0; j < 4; ++j) {
        if constexpr (EPI == 2) {
            c0[j] = p.pu[bz * SEQ + gnv[j]];
            c1[j] = p.pw[bz * SEQ + gnv[j]];
            c2[j] = p.pz[bz * SEQ + gnv[j]];
        } else if constexpr (EPI == 4 || EPI == 5 || EPI == 6 || EPI == 9) {
            c0[j] = p.biasN[gnv[j]];
        }
    }

    #pragma unroll
    for (int i = 0; i < 4; ++i) {
        #pragma unroll
        for (int r = 0; r < 4; ++r) {
            const int gm = bm * 128 + wm * 64 + i * 16 + ((L >> 4) << 2) + r;
            float rA = 0.f, rB = 0.f, mult = 1.f;
            if constexpr (EPI == 2) { rA = p.pe0[bz * SEQ + gm]; rB = p.pe1[bz * SEQ + gm]; }
            if constexpr (EPI == 3) mult = 1.0f / p.pl[bz * SEQ + gm];
            if constexpr (EPI == 8) rA = p.biasM[gm];
            #pragma unroll
            for (int j = 0; j < 4; ++j) {
                float v = acc[i][j][r];
                const long long oidx = obase + (long long)gm * p.ldo + gnv[j];
                if constexpr (EPI == 2) {
                    float s = v * p.scale + rA * c0[j] + rB * c1[j] + c2[j];
                    Of[oidx] = (gnv[j] <= gm) ? __expf(s) : 0.f;
                } else if constexpr (EPI == 3) {
                    float val = v * mult;
                    ushortT h = f2b(val);
                    Oh[oidx] = h; Ol[oidx] = f2b(val - b2f(h));
                } else if constexpr (EPI == 4) {
                    Of[oidx] = v + c0[j] + p.resF32[(long long)gm * p.ldo + gnv[j]];
                } else if constexpr (EPI == 5) {
                    float tt = v + c0[j];
                    Oh[oidx] = f2b(0.5f * tt * (1.0f + erff(tt * 0.70710678118654752f)));
                } else if constexpr (EPI == 6) {
                    float val = v + c0[j];
                    ushortT h = f2b(val);
                    Oh[oidx] = h; Ol[oidx] = f2b(val - b2f(h));
                } else if constexpr (EPI == 8) {
                    float val = v + rA;
                    ushortT h = f2b(val);
                    Oh[oidx] = h; Ol[oidx] = f2b(val - b2f(h));
                } else if constexpr (EPI == 9) {
                    Of[oidx] = v + c0[j];
                }
            }
        }
    }
}

// ------------------------------- host driver --------------------------------
extern "C" void kernel_launch(void* const* d_in, const int* in_sizes, int n_in,
                              void* d_out, int out_size, void* d_ws, size_t ws_size,
                              hipStream_t stream) {
    (void)in_sizes; (void)n_in; (void)out_size; (void)ws_size;
    const float* x    = (const float*)d_in[0];
    const float* wq   = (const float*)d_in[2];
    const float* bq   = (const float*)d_in[3];
    const float* wk   = (const float*)d_in[4];
    const float* bk   = (const float*)d_in[5];
    const float* wv   = (const float*)d_in[6];
    const float* bv   = (const float*)d_in[7];
    const float* wo   = (const float*)d_in[8];
    const float* bo   = (const float*)d_in[9];
    const float* ln1g = (const float*)d_in[10];
    const float* ln1b = (const float*)d_in[11];
    const float* ln2g = (const float*)d_in[12];
    const float* ln2b = (const float*)d_in[13];
    const float* fc1w = (const float*)d_in[14];
    const float* fc1b = (const float*)d_in[15];
    const float* fc2w = (const float*)d_in[16];
    const float* fc2b = (const float*)d_in[17];
    const float* rww  = (const float*)d_in[18];
    const float* rwb  = (const float*)d_in[19];
    const float* cw   = (const float*)d_in[20];
    const float* cb   = (const float*)d_in[21];
    const float* ew   = (const float*)d_in[22];
    const float* eb   = (const float*)d_in[23];
    const float* st   = (const float*)d_in[24];

    char* ws = (char*)d_ws;
    const size_t MB32 = 33554432;
    // Attention: s0 h1hi, s1 h1lo, s2 qhi, s3 qlo, s4 khi, s5 klo, s6 vthi, s7 vtlo
    // After scores: ctxhi->s2, ctxlo->s3 | x1 f32 -> s0+s1 | h2 -> s4,s5
    // FFN: fw (fc1h,fc2h,rwh,rwl) -> s6 | ffc -> s2 | logc -> s7
    ushortT* h1hi = (ushortT*)(ws + 0 * MB32);
    ushortT* h1lo = (ushortT*)(ws + 1 * MB32);
    ushortT* qhi  = (ushortT*)(ws + 2 * MB32);
    ushortT* qlo  = (ushortT*)(ws + 3 * MB32);
    ushortT* khi  = (ushortT*)(ws + 4 * MB32);
    ushortT* klo  = (ushortT*)(ws + 5 * MB32);
    ushortT* vthi = (ushortT*)(ws + 6 * MB32);
    ushortT* vtlo = (ushortT*)(ws + 7 * MB32);
    ushortT* ctxhi = qhi;
    ushortT* ctxlo = qlo;
    float*   x1   = (float*)(ws + 0 * MB32);
    ushortT* h2hi = khi;
    ushortT* h2lo = klo;
    ushortT* fw   = vthi;
    ushortT* ffc  = (ushortT*)(ws + 2 * MB32);
    float*   logc = (float*)(ws + 7 * MB32);
    char* tail = ws + 8 * MB32;
    ushortT* whi = (ushortT*)(tail);                    // 2MB JIT weight hi
    ushortT* wlo = (ushortT*)(tail + 2097152);          // 2MB JIT weight lo
    char* sm = tail + 4194304;
    float* e0v = (float*)(sm);
    float* e1v = (float*)(sm + 1 * 65536);
    float* uu  = (float*)(sm + 2 * 65536);
    float* wwp = (float*)(sm + 3 * 65536);
    float* zz  = (float*)(sm + 4 * 65536);
    float* lrow = (float*)(sm + 5 * 65536);

    const int NW = HDIM * HDIM;
    const int NF = DFF * HDIM;
    ushortT* fc1h = fw;
    ushortT* fc2h = fw + 1 * (size_t)NF;
    ushortT* rwh  = fw + 2 * (size_t)NF;
    ushortT* rwl  = fw + 3 * (size_t)NF;

    float* outx = (float*)d_out;
    float* attn = outx + (size_t)TOK * HDIM;    // f32 [B,1,S,S]

    // --- attention sub-block ---
    ln_k<<<TOK, 256, 0, stream>>>(x, h1hi, h1lo, ln1g, ln1b);

    // q = h1*wq^T + bq  -> hi+lo   (h1 hi+lo x wq hi+lo JIT: 3 passes)
    cvt2_k<1><<<NW / 1024, 256, 0, stream>>>(wq, whi, wlo);
    GemmP pq{};
    pq.A = h1hi; pq.A2 = h1lo; pq.B = whi; pq.B2 = wlo;
    pq.lda = HDIM; pq.ldb = HDIM; pq.K = HDIM; pq.ldo = HDIM;
    pq.out = qhi; pq.out2 = qlo; pq.biasN = bq;
    gemm_nt<6, 3, 1><<<dim3(8, 128, 1), 256, 0, stream>>>(pq);

    cvt2_k<1><<<NW / 1024, 256, 0, stream>>>(wk, whi, wlo);
    pq.out = khi; pq.out2 = klo; pq.biasN = bk;
    gemm_nt<6, 3, 1><<<dim3(8, 128, 1), 256, 0, stream>>>(pq);

    // vt[d,t] = wv[d,:]*h1[t,:] + bv[d]  -> hi+lo
    cvt2_k<1><<<NW / 1024, 256, 0, stream>>>(wv, whi, wlo);
    GemmP pv{};
    pv.A = whi; pv.A2 = wlo; pv.B = h1hi; pv.B2 = h1lo;
    pv.lda = HDIM; pv.ldb = HDIM; pv.K = HDIM; pv.ldo = SEQ;
    pv.aBatch = 0; pv.bBatch = (long long)SEQ * HDIM; pv.oBatch = (long long)HDIM * SEQ;
    pv.out = vthi; pv.out2 = vtlo; pv.biasM = bv;
    gemm_nt<8, 3, 1><<<dim3(32, 8, 4), 256, 0, stream>>>(pv);

    bias_pre<<<4096, 256, 0, stream>>>(h1hi, h1lo, cw, cb, ew, eb, st, e0v, e1v, uu, wwp, zz);

    // scores -> exp (q hi+lo x k hi+lo: pure gload_lds, 3 passes)
    GemmP ps{};
    ps.A = qhi; ps.A2 = qlo; ps.B = khi; ps.B2 = klo;
    ps.lda = HDIM; ps.ldb = HDIM; ps.K = HDIM; ps.ldo = SEQ;
    ps.aBatch = (long long)SEQ * HDIM; ps.bBatch = (long long)SEQ * HDIM;
    ps.oBatch = (long long)SEQ * SEQ;
    ps.out = attn; ps.scale = 0.03125f;  // 1/sqrt(1024)
    ps.pe0 = e0v; ps.pe1 = e1v; ps.pu = uu; ps.pw = wwp; ps.pz = zz;
    gemm_nt<2, 3, 1><<<dim3(32, 32, 4), 256, 0, stream>>>(ps);

    row_sum<<<TOK, 256, 0, stream>>>(attn, lrow);

    // ctx = (e * vt^T) / l -> hi+lo   (e f32 staged, vt hi+lo gload_lds)
    GemmP pp{};
    pp.Af = attn; pp.B = vthi; pp.B2 = vtlo;
    pp.lda = SEQ; pp.ldb = SEQ; pp.K = SEQ; pp.ldo = HDIM;
    pp.aBatch = (long long)SEQ * SEQ; pp.bBatch = (long long)HDIM * SEQ;
    pp.oBatch = (long long)SEQ * HDIM;
    pp.out = ctxhi; pp.out2 = ctxlo; pp.pl = lrow;
    gemm_nt<3, 2, 1><<<dim3(8, 32, 4), 256, 0, stream>>>(pp);

    attn_norm<<<32768, 256, 0, stream>>>(attn, lrow);

    // x1 = x + ctx*wo^T + bo  (ctx hi+lo x wo hi+lo JIT)
    cvt2_k<1><<<NW / 1024, 256, 0, stream>>>(wo, whi, wlo);
    GemmP po{};
    po.A = ctxhi; po.A2 = ctxlo; po.B = whi; po.B2 = wlo;
    po.lda = HDIM; po.ldb = HDIM; po.K = HDIM; po.ldo = HDIM;
    po.out = x1; po.biasN = bo; po.resF32 = x;
    gemm_nt<4, 3, 1><<<dim3(8, 128, 1), 256, 0, stream>>>(po);

    // --- sparse FFN sub-block ---
    ln_k<<<TOK, 256, 0, stream>>>(x1, h2hi, h2lo, ln2g, ln2b);

    cvt2_k<0><<<NF / 1024, 256, 0, stream>>>(fc1w, fc1h, nullptr);
    cvt2_k<0><<<NF / 1024, 256, 0, stream>>>(fc2w, fc2h, nullptr);
    cvt2_k<1><<<NF / 1024, 256, 0, stream>>>(rww, rwh, rwl);

    for (int c = 0; c < 8; ++c) {
        const size_t roff = (size_t)c * 2048 * HDIM;
        GemmP pf{};
        pf.A = h2hi + roff; pf.B = fc1h;
        pf.lda = HDIM; pf.ldb = HDIM; pf.K = HDIM; pf.ldo = DFF;
        pf.out = ffc; pf.biasN = fc1b;
        gemm_nt<5, 0, 0><<<dim3(32, 16, 1), 256, 0, stream>>>(pf);

        GemmP pr{};
        pr.A = h2hi + roff; pr.A2 = h2lo + roff; pr.B = rwh; pr.B2 = rwl;
        pr.lda = HDIM; pr.ldb = HDIM; pr.K = HDIM; pr.ldo = DFF;
        pr.out = logc; pr.biasN = rwb;
        gemm_nt<9, 3, 1><<<dim3(32, 16, 1), 256, 0, stream>>>(pr);

        topk_mask<<<2048, 256, 0, stream>>>(logc, ffc);

        GemmP p2{};
        p2.A = ffc; p2.B = fc2h; p2.lda = DFF; p2.ldb = DFF; p2.K = DFF; p2.ldo = HDIM;
        p2.out = outx + roff; p2.biasN = fc2b;
        p2.resF32 = x1 + roff;
        gemm_nt<4, 0, 0><<<dim3(8, 16, 1), 256, 0, stream>>>(p2);
    }
}

// Round 9
// 3033.990 us; speedup vs baseline: 1.3541x; 1.1603x over previous
//
#include <hip/hip_runtime.h>

// CausalTransformerBlock: B=4, S=4096, H=1024, NH=1, D_FF=4096, ktop=409.
// r8 PASSED 3520us. r9: (a) FIXED XOR swizzle s(row)=(row>>1)&3 -- r8's
// (row&3) left 2-way conflicts in every 8-lane batch (quads (4r+r&3)%8
// alias); correct form gives a perfect 8-quad permutation per batch.
// (b) early-zero path for fully-masked score tiles. (c) FFN chunks 8->4
// (logc 64MB over s2+s3, ffc over s7).
// Numerics identical to r8 (swizzle is a value-neutral permutation).
// ws: 8*32MiB + 4MiB + 384KiB = 273,022,976 B (proven in r7/r8).

typedef unsigned short ushortT;
typedef short bf16x8 __attribute__((ext_vector_type(8)));
typedef float f32x4 __attribute__((ext_vector_type(4)));
typedef unsigned short us8 __attribute__((ext_vector_type(8)));

#define SEQ 4096
#define HDIM 1024
#define TOK 16384
#define DFF 4096
#define KTOP 409

__device__ __forceinline__ float b2f(unsigned short u) {
    return __uint_as_float(((unsigned)u) << 16);
}
__device__ __forceinline__ unsigned short f2b(float f) {
    unsigned u = __float_as_uint(f);
    u += 0x7fffu + ((u >> 16) & 1u);   // RNE
    return (unsigned short)(u >> 16);
}

__device__ __forceinline__ float blkRedF(float v, float* red4) {
    #pragma unroll
    for (int o = 32; o; o >>= 1) v += __shfl_xor(v, o);
    if ((threadIdx.x & 63) == 0) red4[threadIdx.x >> 6] = v;
    __syncthreads();
    v = red4[0] + red4[1] + red4[2] + red4[3];
    __syncthreads();
    return v;
}
__device__ __forceinline__ int blkRedI(int v, int* red4) {
    #pragma unroll
    for (int o = 32; o; o >>= 1) v += __shfl_xor(v, o);
    if ((threadIdx.x & 63) == 0) red4[threadIdx.x >> 6] = v;
    __syncthreads();
    v = red4[0] + red4[1] + red4[2] + red4[3];
    __syncthreads();
    return v;
}

// -------- f32 -> bf16 hi (+ optional lo residual) convert -------------------
template<int HASLO>
__global__ __launch_bounds__(256) void cvt2_k(const float* __restrict__ s,
                                              ushortT* __restrict__ hi,
                                              ushortT* __restrict__ lo) {
    const int i = (blockIdx.x * 256 + threadIdx.x) * 4;
    float4 v = *(const float4*)(s + i);
    float vv[4] = {v.x, v.y, v.z, v.w};
    ushort4 h, l;
    unsigned short* hp = &h.x; unsigned short* lp = &l.x;
    #pragma unroll
    for (int j = 0; j < 4; ++j) {
        hp[j] = f2b(vv[j]);
        if constexpr (HASLO) lp[j] = f2b(vv[j] - b2f(hp[j]));
    }
    *(ushort4*)(hi + i) = h;
    if constexpr (HASLO) *(ushort4*)(lo + i) = l;
}

// ---------------- LayerNorm: f32 in -> bf16 hi+lo out ------------------------
__global__ __launch_bounds__(256) void ln_k(const float* __restrict__ in,
                                            ushortT* __restrict__ ohi,
                                            ushortT* __restrict__ olo,
                                            const float* __restrict__ g,
                                            const float* __restrict__ b) {
    __shared__ float red4[4];
    const long long row = blockIdx.x;
    const int t = threadIdx.x;
    float4 v = ((const float4*)(in + row * HDIM))[t];
    float x[4] = {v.x, v.y, v.z, v.w};
    float s = x[0] + x[1] + x[2] + x[3];
    s = blkRedF(s, red4);
    const float mean = s * (1.0f / HDIM);
    float vs = 0.f;
    #pragma unroll
    for (int k2 = 0; k2 < 4; ++k2) { float d = x[k2] - mean; vs += d * d; }
    vs = blkRedF(vs, red4);
    const float inv = 1.0f / sqrtf(vs * (1.0f / HDIM) + 1e-5f);
    float4 gv = ((const float4*)g)[t];
    float4 bv = ((const float4*)b)[t];
    float o[4];
    o[0] = (x[0] - mean) * inv * gv.x + bv.x;
    o[1] = (x[1] - mean) * inv * gv.y + bv.y;
    o[2] = (x[2] - mean) * inv * gv.z + bv.z;
    o[3] = (x[3] - mean) * inv * gv.w + bv.w;
    ushort4 h, l;
    unsigned short* hp = &h.x; unsigned short* lp = &l.x;
    #pragma unroll
    for (int j = 0; j < 4; ++j) {
        hp[j] = f2b(o[j]);
        lp[j] = f2b(o[j] - b2f(hp[j]));
    }
    ((ushort4*)(ohi + row * HDIM))[t] = h;
    ((ushort4*)(olo + row * HDIM))[t] = l;
}

// ------------- rank-3 causal-bias precompute (h1 = hi+lo bf16) --------------
__global__ __launch_bounds__(256) void bias_pre(const ushortT* __restrict__ hhi,
        const ushortT* __restrict__ hlo,
        const float* __restrict__ cw, const float* __restrict__ cb,
        const float* __restrict__ ew, const float* __restrict__ eb,
        const float* __restrict__ st,
        float* __restrict__ e0, float* __restrict__ e1,
        float* __restrict__ uu, float* __restrict__ ww, float* __restrict__ zz) {
    const int tok = blockIdx.x * 4 + (threadIdx.x >> 6);
    const int L = threadIdx.x & 63;
    const long long base = (long long)tok * HDIM + L * 16;
    float d0 = 0, d1 = 0, du = 0, dw = 0, dz = 0;
    #pragma unroll
    for (int q = 0; q < 16; ++q) {
        float hv = b2f(hhi[base + q]) + b2f(hlo[base + q]);
        d0 += hv * cw[L * 16 + q];
        d1 += hv * cw[HDIM + L * 16 + q];
        du += hv * ew[L * 16 + q];
        dw += hv * ew[HDIM + L * 16 + q];
        dz += hv * (eb[L * 16 + q] + eb[HDIM + L * 16 + q]);
    }
    #pragma unroll
    for (int o = 32; o; o >>= 1) {
        d0 += __shfl_xor(d0, o); d1 += __shfl_xor(d1, o);
        du += __shfl_xor(du, o); dw += __shfl_xor(dw, o); dz += __shfl_xor(dz, o);
    }
    if (L == 0) {
        e0[tok] = (d0 + cb[0]) * st[0];
        e1[tok] = (d1 + cb[1]) * st[1];
        uu[tok] = du; ww[tok] = dw; zz[tok] = dz;
    }
}

// ---------------- deterministic row-sum of f32 exp-scores -------------------
__global__ __launch_bounds__(256) void row_sum(const float* __restrict__ e,
                                               float* __restrict__ l) {
    __shared__ float red4[4];
    const long long row = blockIdx.x;
    const float4* p = (const float4*)(e + row * (long long)SEQ + threadIdx.x * 16);
    float s = 0.f;
    #pragma unroll
    for (int i = 0; i < 4; ++i) {
        float4 v = p[i];
        s += v.x + v.y + v.z + v.w;
    }
    s = blkRedF(s, red4);
    if (threadIdx.x == 0) l[row] = s;
}

// ---------------- normalize attn in place: e *= 1/l[row] (f32) --------------
__global__ __launch_bounds__(256) void attn_norm(float* __restrict__ attn,
                                                 const float* __restrict__ l) {
    const long long g = (long long)blockIdx.x * 256 + threadIdx.x;
    const long long base = g * 8;
    const float inv = 1.0f / l[base >> 12];
    float4 v0 = *(const float4*)(attn + base);
    float4 v1 = *(const float4*)(attn + base + 4);
    v0.x *= inv; v0.y *= inv; v0.z *= inv; v0.w *= inv;
    v1.x *= inv; v1.y *= inv; v1.z *= inv; v1.w *= inv;
    *(float4*)(attn + base) = v0;
    *(float4*)(attn + base + 4) = v1;
}

// ------- exact top-409 select + mask-apply (binary search on key bits) ------
__global__ __launch_bounds__(256) void topk_mask(const float* __restrict__ logits,
                                                 ushortT* __restrict__ ff) {
    __shared__ int red4[4];
    __shared__ int sc[256];
    const long long row = blockIdx.x;
    const int t = threadIdx.x;
    const float* lg = logits + row * (long long)DFF + t * 16;
    unsigned key[16];
    #pragma unroll
    for (int q4 = 0; q4 < 4; ++q4) {
        float4 v = ((const float4*)lg)[q4];
        float vv[4] = {v.x, v.y, v.z, v.w};
        #pragma unroll
        for (int j = 0; j < 4; ++j) {
            unsigned u = __float_as_uint(vv[j]);
            key[q4 * 4 + j] = (u & 0x80000000u) ? ~u : (u | 0x80000000u);
        }
    }
    unsigned T = 0;
    for (int bit = 31; bit >= 0; --bit) {
        unsigned cand = T | (1u << bit);
        int c = 0;
        #pragma unroll
        for (int q = 0; q < 16; ++q) c += (key[q] >= cand);
        c = blkRedI(c, red4);
        if (c >= KTOP) T = cand;
    }
    int cg = 0, eq = 0;
    #pragma unroll
    for (int q = 0; q < 16; ++q) { cg += (key[q] > T); eq += (key[q] == T); }
    cg = blkRedI(cg, red4);
    const int need = KTOP - cg;
    sc[t] = eq;
    __syncthreads();
    for (int o = 1; o < 256; o <<= 1) {
        int x = (t >= o) ? sc[t - o] : 0;
        __syncthreads();
        sc[t] += x;
        __syncthreads();
    }
    int pre = sc[t] - eq;   // exclusive prefix of equal-count, index order
    ushortT* fr = ff + row * (long long)DFF + t * 16;
    #pragma unroll
    for (int q = 0; q < 16; ++q) {
        bool sel = (key[q] > T) || ((key[q] == T) && (pre < need));
        if (key[q] == T) pre++;
        if (!sel) fr[q] = 0;
    }
}

// ---------------- unified NT GEMM: C[M,N] = A[M,K] * B[N,K]^T ----------------
// 128x128 tile, 4 waves, BK=32, global_load_lds(16B), XOR chunk-swizzle
// s(row) = (row>>1)&3 (perfect 8-quad permutation per 8-lane batch).
//  AMODE: 0=A bf16 hi gload_lds; 2=A f32 -> hi+lo VALU-staged; 3=A hi+lo gload_lds
//  BMODE: 0=B bf16 hi gload_lds; 1=B hi+lo gload_lds
// Passes: hi*hi [+ hi*lo if BMODE==1] [+ lo*hi if AMODE>=2].
struct GemmP {
    const ushortT* A; const ushortT* A2; const float* Af;
    const ushortT* B; const ushortT* B2;
    long long aBatch, bBatch, oBatch;
    int lda, ldb, K, ldo;
    void* out; void* out2;
    const float* biasN; const float* biasM;
    const float *pe0, *pe1, *pu, *pw, *pz, *pl;
    const float* resF32;
    float scale;
};

// EPI: 2=f32 exp-scores(causal)  3=hi+lo PV*(1/l)  4=f32+biasN+resF32
//      5=gelu(.+biasN) bf16  6=hi+lo +biasN  8=hi+lo +biasM  9=f32+biasN
template<int EPI, int AMODE, int BMODE>
__global__ __launch_bounds__(256) void gemm_nt(GemmP p) {
    __shared__ ushortT Ahi[4096];
    __shared__ ushortT Bhi[4096];
    __shared__ ushortT Alo[(AMODE >= 2) ? 4096 : 8];
    __shared__ ushortT Blo[(BMODE == 1) ? 4096 : 8];
    const int tid = threadIdx.x;
    const int L = tid & 63;
    const int w = tid >> 6;
    const int wm = w >> 1, wn = w & 1;
    const int bn = blockIdx.x, bm = blockIdx.y, bz = blockIdx.z;

    f32x4 acc[4][4] = {};

    const long long obase = (long long)bz * p.oBatch;
    float* Of = (float*)p.out;
    ushortT* Oh = (ushortT*)p.out;
    ushortT* Ol = (ushortT*)p.out2;

    int gnv[4];
    #pragma unroll
    for (int j = 0; j < 4; ++j) gnv[j] = bn * 128 + wn * 64 + j * 16 + (L & 15);

    if constexpr (EPI == 2) {
        if (bn > bm) {   // fully-masked tile: zeros, no exp/bias work
            #pragma unroll
            for (int i = 0; i < 4; ++i)
                #pragma unroll
                for (int r = 0; r < 4; ++r) {
                    const int gm = bm * 128 + wm * 64 + i * 16 + ((L >> 4) << 2) + r;
                    #pragma unroll
                    for (int j = 0; j < 4; ++j)
                        Of[obase + (long long)gm * p.ldo + gnv[j]] = 0.f;
                }
            return;
        }
    }

    int kEnd = p.K;
    if constexpr (EPI == 3) { kEnd = min(p.K, (bm + 1) * 128); }

    // gload_lds dest is linear (lane*16B); pre-swizzle the SOURCE chunk so
    // LDS[row][c] = global[row][c ^ s(row)], s(row)=(row>>1)&3; reads XOR same.
    const int r0row = tid >> 2;
    const int r1row = 64 + r0row;
    const int rc   = ((tid & 3) ^ ((tid >> 3) & 3)) * 8;    // source chunk
    const int qsw  = (((L >> 4) ^ ((L >> 1) & 3))) * 8;     // read chunk

    for (int k0 = 0; k0 < kEnd; k0 += 32) {
        // ---- stage A ----
        if constexpr (AMODE != 2) {
            const ushortT* Ab = p.A + (long long)bz * p.aBatch
                              + (long long)bm * 128 * p.lda + k0 + rc;
            __builtin_amdgcn_global_load_lds(
                (const __attribute__((address_space(1))) void*)(Ab + (long long)r0row * p.lda),
                (__attribute__((address_space(3))) void*)(Ahi + w * 512), 16, 0, 0);
            __builtin_amdgcn_global_load_lds(
                (const __attribute__((address_space(1))) void*)(Ab + (long long)r1row * p.lda),
                (__attribute__((address_space(3))) void*)(Ahi + 2048 + w * 512), 16, 0, 0);
            if constexpr (AMODE == 3) {
                const ushortT* Ab2 = p.A2 + (long long)bz * p.aBatch
                                   + (long long)bm * 128 * p.lda + k0 + rc;
                __builtin_amdgcn_global_load_lds(
                    (const __attribute__((address_space(1))) void*)(Ab2 + (long long)r0row * p.lda),
                    (__attribute__((address_space(3))) void*)(Alo + w * 512), 16, 0, 0);
                __builtin_amdgcn_global_load_lds(
                    (const __attribute__((address_space(1))) void*)(Ab2 + (long long)r1row * p.lda),
                    (__attribute__((address_space(3))) void*)(Alo + 2048 + w * 512), 16, 0, 0);
            }
        } else {
            const int arow = tid >> 1;
            const float* ap = p.Af + (long long)bz * p.aBatch
                            + ((long long)bm * 128 + arow) * p.lda
                            + k0 + (tid & 1) * 16;
            #pragma unroll
            for (int cc = 0; cc < 2; ++cc) {
                const int c = (tid & 1) * 2 + cc;
                const int cs = (c ^ ((arow >> 1) & 3)) * 8;   // swizzled dest chunk
                float4 v0 = ((const float4*)ap)[cc * 2];
                float4 v1 = ((const float4*)ap)[cc * 2 + 1];
                float vv[8] = {v0.x, v0.y, v0.z, v0.w, v1.x, v1.y, v1.z, v1.w};
                us8 h, l;
                #pragma unroll
                for (int j = 0; j < 8; ++j) {
                    h[j] = f2b(vv[j]);
                    l[j] = f2b(vv[j] - b2f(h[j]));
                }
                *(us8*)(Ahi + arow * 32 + cs) = h;
                *(us8*)(Alo + arow * 32 + cs) = l;
            }
        }
        // ---- stage B ----
        {
            const ushortT* Bb = p.B + (long long)bz * p.bBatch
                              + (long long)bn * 128 * p.ldb + k0 + rc;
            __builtin_amdgcn_global_load_lds(
                (const __attribute__((address_space(1))) void*)(Bb + (long long)r0row * p.ldb),
                (__attribute__((address_space(3))) void*)(Bhi + w * 512), 16, 0, 0);
            __builtin_amdgcn_global_load_lds(
                (const __attribute__((address_space(1))) void*)(Bb + (long long)r1row * p.ldb),
                (__attribute__((address_space(3))) void*)(Bhi + 2048 + w * 512), 16, 0, 0);
            if constexpr (BMODE == 1) {
                const ushortT* Bb2 = p.B2 + (long long)bz * p.bBatch
                                   + (long long)bn * 128 * p.ldb + k0 + rc;
                __builtin_amdgcn_global_load_lds(
                    (const __attribute__((address_space(1))) void*)(Bb2 + (long long)r0row * p.ldb),
                    (__attribute__((address_space(3))) void*)(Blo + w * 512), 16, 0, 0);
                __builtin_amdgcn_global_load_lds(
                    (const __attribute__((address_space(1))) void*)(Bb2 + (long long)r1row * p.ldb),
                    (__attribute__((address_space(3))) void*)(Blo + 2048 + w * 512), 16, 0, 0);
            }
        }
        __syncthreads();
        {
            bf16x8 ah[4], bh[4];
            #pragma unroll
            for (int i = 0; i < 4; ++i)
                ah[i] = *(const bf16x8*)(Ahi + (wm * 64 + i * 16 + (L & 15)) * 32 + qsw);
            #pragma unroll
            for (int j = 0; j < 4; ++j)
                bh[j] = *(const bf16x8*)(Bhi + (wn * 64 + j * 16 + (L & 15)) * 32 + qsw);
            #pragma unroll
            for (int i = 0; i < 4; ++i)
                #pragma unroll
                for (int j = 0; j < 4; ++j)
                    acc[i][j] = __builtin_amdgcn_mfma_f32_16x16x32_bf16(ah[i], bh[j], acc[i][j], 0, 0, 0);
            if constexpr (BMODE == 1) {
                bf16x8 bl[4];
                #pragma unroll
                for (int j = 0; j < 4; ++j)
                    bl[j] = *(const bf16x8*)(Blo + (wn * 64 + j * 16 + (L & 15)) * 32 + qsw);
                #pragma unroll
                for (int i = 0; i < 4; ++i)
                    #pragma unroll
                    for (int j = 0; j < 4; ++j)
                        acc[i][j] = __builtin_amdgcn_mfma_f32_16x16x32_bf16(ah[i], bl[j], acc[i][j], 0, 0, 0);
            }
            if constexpr (AMODE >= 2) {
                bf16x8 al[4];
                #pragma unroll
                for (int i = 0; i < 4; ++i)
                    al[i] = *(const bf16x8*)(Alo + (wm * 64 + i * 16 + (L & 15)) * 32 + qsw);
                #pragma unroll
                for (int i = 0; i < 4; ++i)
                    #pragma unroll
                    for (int j = 0; j < 4; ++j)
                        acc[i][j] = __builtin_amdgcn_mfma_f32_16x16x32_bf16(al[i], bh[j], acc[i][j], 0, 0, 0);
            }
        }
        __syncthreads();
    }

    float c0[4], c1[4], c2[4];
    #pragma unroll
    for (int j = 0; j < 4; ++j) {
        if constexpr (EPI == 2) {
            c0[j] = p.pu[bz * SEQ + gnv[j]];
            c1[j] = p.pw[bz * SEQ + gnv[j]];
            c2[j] = p.pz[bz * SEQ + gnv[j]];
        } else if constexpr (EPI == 4 || EPI == 5 || EPI == 6 || EPI == 9) {
            c0[j] = p.biasN[gnv[j]];
        }
    }

    #pragma unroll
    for (int i = 0; i < 4; ++i) {
        #pragma unroll
        for (int r = 0; r < 4; ++r) {
            const int gm = bm * 128 + wm * 64 + i * 16 + ((L >> 4) << 2) + r;
            float rA = 0.f, rB = 0.f, mult = 1.f;
            if constexpr (EPI == 2) { rA = p.pe0[bz * SEQ + gm]; rB = p.pe1[bz * SEQ + gm]; }
            if constexpr (EPI == 3) mult = 1.0f / p.pl[bz * SEQ + gm];
            if constexpr (EPI == 8) rA = p.biasM[gm];
            #pragma unroll
            for (int j = 0; j < 4; ++j) {
                float v = acc[i][j][r];
                const long long oidx = obase + (long long)gm * p.ldo + gnv[j];
                if constexpr (EPI == 2) {
                    float s = v * p.scale + rA * c0[j] + rB * c1[j] + c2[j];
                    Of[oidx] = (gnv[j] <= gm) ? __expf(s) : 0.f;
                } else if constexpr (EPI == 3) {
                    float val = v * mult;
                    ushortT h = f2b(val);
                    Oh[oidx] = h; Ol[oidx] = f2b(val - b2f(h));
                } else if constexpr (EPI == 4) {
                    Of[oidx] = v + c0[j] + p.resF32[(long long)gm * p.ldo + gnv[j]];
                } else if constexpr (EPI == 5) {
                    float tt = v + c0[j];
                    Oh[oidx] = f2b(0.5f * tt * (1.0f + erff(tt * 0.70710678118654752f)));
                } else if constexpr (EPI == 6) {
                    float val = v + c0[j];
                    ushortT h = f2b(val);
                    Oh[oidx] = h; Ol[oidx] = f2b(val - b2f(h));
                } else if constexpr (EPI == 8) {
                    float val = v + rA;
                    ushortT h = f2b(val);
                    Oh[oidx] = h; Ol[oidx] = f2b(val - b2f(h));
                } else if constexpr (EPI == 9) {
                    Of[oidx] = v + c0[j];
                }
            }
        }
    }
}

// ------------------------------- host driver --------------------------------
extern "C" void kernel_launch(void* const* d_in, const int* in_sizes, int n_in,
                              void* d_out, int out_size, void* d_ws, size_t ws_size,
                              hipStream_t stream) {
    (void)in_sizes; (void)n_in; (void)out_size; (void)ws_size;
    const float* x    = (const float*)d_in[0];
    const float* wq   = (const float*)d_in[2];
    const float* bq   = (const float*)d_in[3];
    const float* wk   = (const float*)d_in[4];
    const float* bk   = (const float*)d_in[5];
    const float* wv   = (const float*)d_in[6];
    const float* bv   = (const float*)d_in[7];
    const float* wo   = (const float*)d_in[8];
    const float* bo   = (const float*)d_in[9];
    const float* ln1g = (const float*)d_in[10];
    const float* ln1b = (const float*)d_in[11];
    const float* ln2g = (const float*)d_in[12];
    const float* ln2b = (const float*)d_in[13];
    const float* fc1w = (const float*)d_in[14];
    const float* fc1b = (const float*)d_in[15];
    const float* fc2w = (const float*)d_in[16];
    const float* fc2b = (const float*)d_in[17];
    const float* rww  = (const float*)d_in[18];
    const float* rwb  = (const float*)d_in[19];
    const float* cw   = (const float*)d_in[20];
    const float* cb   = (const float*)d_in[21];
    const float* ew   = (const float*)d_in[22];
    const float* eb   = (const float*)d_in[23];
    const float* st   = (const float*)d_in[24];

    char* ws = (char*)d_ws;
    const size_t MB32 = 33554432;
    // s0 h1hi, s1 h1lo, s2 qhi, s3 qlo, s4 khi, s5 klo, s6 vthi, s7 vtlo
    // After scores: ctx hi/lo -> s2,s3 | x1 f32 -> s0+s1 | h2 -> s4,s5
    // FFN: fw -> s6 (32MB) | logc f32 -> s2+s3 (64MB) | ffc bf16 -> s7 (32MB)
    ushortT* h1hi = (ushortT*)(ws + 0 * MB32);
    ushortT* h1lo = (ushortT*)(ws + 1 * MB32);
    ushortT* qhi  = (ushortT*)(ws + 2 * MB32);
    ushortT* qlo  = (ushortT*)(ws + 3 * MB32);
    ushortT* khi  = (ushortT*)(ws + 4 * MB32);
    ushortT* klo  = (ushortT*)(ws + 5 * MB32);
    ushortT* vthi = (ushortT*)(ws + 6 * MB32);
    ushortT* vtlo = (ushortT*)(ws + 7 * MB32);
    ushortT* ctxhi = qhi;
    ushortT* ctxlo = qlo;
    float*   x1   = (float*)(ws + 0 * MB32);
    ushortT* h2hi = khi;
    ushortT* h2lo = klo;
    ushortT* fw   = vthi;
    float*   logc = (float*)(ws + 2 * MB32);
    ushortT* ffc  = (ushortT*)(ws + 7 * MB32);
    char* tail = ws + 8 * MB32;
    ushortT* whi = (ushortT*)(tail);                    // 2MB JIT weight hi
    ushortT* wlo = (ushortT*)(tail + 2097152);          // 2MB JIT weight lo
    char* sm = tail + 4194304;
    float* e0v = (float*)(sm);
    float* e1v = (float*)(sm + 1 * 65536);
    float* uu  = (float*)(sm + 2 * 65536);
    float* wwp = (float*)(sm + 3 * 65536);
    float* zz  = (float*)(sm + 4 * 65536);
    float* lrow = (float*)(sm + 5 * 65536);

    const int NW = HDIM * HDIM;
    const int NF = DFF * HDIM;
    ushortT* fc1h = fw;
    ushortT* fc2h = fw + 1 * (size_t)NF;
    ushortT* rwh  = fw + 2 * (size_t)NF;
    ushortT* rwl  = fw + 3 * (size_t)NF;

    float* outx = (float*)d_out;
    float* attn = outx + (size_t)TOK * HDIM;    // f32 [B,1,S,S]

    // --- attention sub-block ---
    ln_k<<<TOK, 256, 0, stream>>>(x, h1hi, h1lo, ln1g, ln1b);

    // q = h1*wq^T + bq  -> hi+lo   (h1 hi+lo x wq hi+lo JIT: 3 passes)
    cvt2_k<1><<<NW / 1024, 256, 0, stream>>>(wq, whi, wlo);
    GemmP pq{};
    pq.A = h1hi; pq.A2 = h1lo; pq.B = whi; pq.B2 = wlo;
    pq.lda = HDIM; pq.ldb = HDIM; pq.K = HDIM; pq.ldo = HDIM;
    pq.out = qhi; pq.out2 = qlo; pq.biasN = bq;
    gemm_nt<6, 3, 1><<<dim3(8, 128, 1), 256, 0, stream>>>(pq);

    cvt2_k<1><<<NW / 1024, 256, 0, stream>>>(wk, whi, wlo);
    pq.out = khi; pq.out2 = klo; pq.biasN = bk;
    gemm_nt<6, 3, 1><<<dim3(8, 128, 1), 256, 0, stream>>>(pq);

    // vt[d,t] = wv[d,:]*h1[t,:] + bv[d]  -> hi+lo
    cvt2_k<1><<<NW / 1024, 256, 0, stream>>>(wv, whi, wlo);
    GemmP pv{};
    pv.A = whi; pv.A2 = wlo; pv.B = h1hi; pv.B2 = h1lo;
    pv.lda = HDIM; pv.ldb = HDIM; pv.K = HDIM; pv.ldo = SEQ;
    pv.aBatch = 0; pv.bBatch = (long long)SEQ * HDIM; pv.oBatch = (long long)HDIM * SEQ;
    pv.out = vthi; pv.out2 = vtlo; pv.biasM = bv;
    gemm_nt<8, 3, 1><<<dim3(32, 8, 4), 256, 0, stream>>>(pv);

    bias_pre<<<4096, 256, 0, stream>>>(h1hi, h1lo, cw, cb, ew, eb, st, e0v, e1v, uu, wwp, zz);

    // scores -> exp (q hi+lo x k hi+lo: pure gload_lds, 3 passes)
    GemmP ps{};
    ps.A = qhi; ps.A2 = qlo; ps.B = khi; ps.B2 = klo;
    ps.lda = HDIM; ps.ldb = HDIM; ps.K = HDIM; ps.ldo = SEQ;
    ps.aBatch = (long long)SEQ * HDIM; ps.bBatch = (long long)SEQ * HDIM;
    ps.oBatch = (long long)SEQ * SEQ;
    ps.out = attn; ps.scale = 0.03125f;  // 1/sqrt(1024)
    ps.pe0 = e0v; ps.pe1 = e1v; ps.pu = uu; ps.pw = wwp; ps.pz = zz;
    gemm_nt<2, 3, 1><<<dim3(32, 32, 4), 256, 0, stream>>>(ps);

    row_sum<<<TOK, 256, 0, stream>>>(attn, lrow);

    // ctx = (e * vt^T) / l -> hi+lo   (e f32 staged, vt hi+lo gload_lds)
    GemmP pp{};
    pp.Af = attn; pp.B = vthi; pp.B2 = vtlo;
    pp.lda = SEQ; pp.ldb = SEQ; pp.K = SEQ; pp.ldo = HDIM;
    pp.aBatch = (long long)SEQ * SEQ; pp.bBatch = (long long)HDIM * SEQ;
    pp.oBatch = (long long)SEQ * HDIM;
    pp.out = ctxhi; pp.out2 = ctxlo; pp.pl = lrow;
    gemm_nt<3, 2, 1><<<dim3(8, 32, 4), 256, 0, stream>>>(pp);

    attn_norm<<<32768, 256, 0, stream>>>(attn, lrow);

    // x1 = x + ctx*wo^T + bo  (ctx hi+lo x wo hi+lo JIT)
    cvt2_k<1><<<NW / 1024, 256, 0, stream>>>(wo, whi, wlo);
    GemmP po{};
    po.A = ctxhi; po.A2 = ctxlo; po.B = whi; po.B2 = wlo;
    po.lda = HDIM; po.ldb = HDIM; po.K = HDIM; po.ldo = HDIM;
    po.out = x1; po.biasN = bo; po.resF32 = x;
    gemm_nt<4, 3, 1><<<dim3(8, 128, 1), 256, 0, stream>>>(po);

    // --- sparse FFN sub-block ---
    ln_k<<<TOK, 256, 0, stream>>>(x1, h2hi, h2lo, ln2g, ln2b);

    cvt2_k<0><<<NF / 1024, 256, 0, stream>>>(fc1w, fc1h, nullptr);
    cvt2_k<0><<<NF / 1024, 256, 0, stream>>>(fc2w, fc2h, nullptr);
    cvt2_k<1><<<NF / 1024, 256, 0, stream>>>(rww, rwh, rwl);

    for (int c = 0; c < 4; ++c) {
        const size_t roff = (size_t)c * 4096 * HDIM;
        GemmP pf{};
        pf.A = h2hi + roff; pf.B = fc1h;
        pf.lda = HDIM; pf.ldb = HDIM; pf.K = HDIM; pf.ldo = DFF;
        pf.out = ffc; pf.biasN = fc1b;
        gemm_nt<5, 0, 0><<<dim3(32, 32, 1), 256, 0, stream>>>(pf);

        GemmP pr{};
        pr.A = h2hi + roff; pr.A2 = h2lo + roff; pr.B = rwh; pr.B2 = rwl;
        pr.lda = HDIM; pr.ldb = HDIM; pr.K = HDIM; pr.ldo = DFF;
        pr.out = logc; pr.biasN = rwb;
        gemm_nt<9, 3, 1><<<dim3(32, 32, 1), 256, 0, stream>>>(pr);

        topk_mask<<<4096, 256, 0, stream>>>(logc, ffc);

        GemmP p2{};
        p2.A = ffc; p2.B = fc2h; p2.lda = DFF; p2.ldb = DFF; p2.K = DFF; p2.ldo = HDIM;
        p2.out = outx + roff; p2.biasN = fc2b;
        p2.resF32 = x1 + roff;
        gemm_nt<4, 0, 0><<<dim3(8, 32, 1), 256, 0, stream>>>(p2);
    }
}